// Round 3
// baseline (344.932 us; speedup 1.0000x reference)
//
#include <hip/hip_runtime.h>
#include <stdint.h>

typedef __attribute__((ext_vector_type(4))) int i32x4;
typedef __attribute__((ext_vector_type(8))) int i32x8;
typedef __attribute__((ext_vector_type(16))) float f32x16;

#define BM 128
#define BN 128
// Quantized operands live in global memory in MFMA-FRAGMENT ORDER:
//   fragment = 32 consecutive K-elements of one row, packed to 16 B (fp4 signs).
//   index16(row, k32) = ((row>>5)*kbT + (k32>>2))*128 + (k32&3)*32 + (row&31)
//   where k32 = k/32, kbT = K/128 (64-B K-tiles per row).
// This makes GEMM staging contiguous (global_load_lds, linear LDS) and the
// fragment ds_read_b128 lane-linear (base + lane*16) -> zero bank conflicts.

// fp4 e2m1 signs: +1 = 0x2, -1 = 0xA, 0 = 0x0 (matches jnp.sign exactly)
__device__ __forceinline__ uint32_t nib4(float v) {
  return v > 0.f ? 0x2u : (v < 0.f ? 0xAu : 0u);
}

// 8 fp32 -> 8 nibbles in one u32 (element j -> nibble j, low nibble first)
__device__ __forceinline__ uint32_t pack8(float4 a, float4 b) {
  return nib4(a.x) | (nib4(a.y) << 4) | (nib4(a.z) << 8) | (nib4(a.w) << 12) |
         (nib4(b.x) << 16) | (nib4(b.y) << 20) | (nib4(b.z) << 24) | (nib4(b.w) << 28);
}

__device__ __forceinline__ float abs4(float4 v) {
  return fabsf(v.x) + fabsf(v.y) + fabsf(v.z) + fabsf(v.w);
}

// ---------------- fused quantize -> fragment-ordered fp4 ----------------
// Blocks [0, halfN): weights, 2 rows per block (128 threads/row), + mean|w| scale.
// Blocks [halfN, halfN+xBlocks): x, 4 fragments per thread.
__global__ __launch_bounds__(256) void quant_fused_kernel(
    const float4* __restrict__ x, uint4* __restrict__ xq,
    const float4* __restrict__ w, uint4* __restrict__ wq,
    float* __restrict__ scale, int halfN, int K, int kbShift) {
  const int t = threadIdx.x;
  const int b = blockIdx.x;
  const int kbT = K >> 7;

  if (b < halfN) {
    // ---- weight rows b*2, b*2+1 ----
    const int row = b * 2 + (t >> 7);
    const int tt = t & 127;  // k32: fragment index within row (K/32 = 128)
    const float4* src = w + ((size_t)row * K >> 2) + tt * 8;
    float4 v0 = src[0], v1 = src[1], v2 = src[2], v3 = src[3];
    float4 v4 = src[4], v5 = src[5], v6 = src[6], v7 = src[7];
    uint4 o;
    o.x = pack8(v0, v1); o.y = pack8(v2, v3);
    o.z = pack8(v4, v5); o.w = pack8(v6, v7);
    size_t fi = ((size_t)(row >> 5) * kbT + (tt >> 2)) * 128 + (tt & 3) * 32 + (row & 31);
    wq[fi] = o;
    float asum = abs4(v0) + abs4(v1) + abs4(v2) + abs4(v3) +
                 abs4(v4) + abs4(v5) + abs4(v6) + abs4(v7);
    for (int off = 32; off > 0; off >>= 1) asum += __shfl_down(asum, off);
    __shared__ float red[4];
    if ((t & 63) == 0) red[t >> 6] = asum;
    __syncthreads();
    if ((t & 127) == 0) scale[row] = (red[t >> 6] + red[(t >> 6) + 1]) / (float)K;
  } else {
    // ---- x fragments: 1024 per block, 4 per thread ----
    const size_t base = (size_t)(b - halfN) * 1024;
#pragma unroll
    for (int j = 0; j < 4; ++j) {
      size_t f = base + (size_t)j * 256 + t;
      size_t g = f >> 7;               // rowblk*kbT + kbblk
      int p2 = (int)(f & 127);
      size_t rowblk = g >> kbShift;
      int kbblk = (int)(g & (kbT - 1));
      size_t row = rowblk * 32 + (p2 & 31);
      int k32 = kbblk * 4 + (p2 >> 5);
      const float4* src = x + ((size_t)row * K >> 2) + k32 * 8;
      float4 v0 = src[0], v1 = src[1], v2 = src[2], v3 = src[3];
      float4 v4 = src[4], v5 = src[5], v6 = src[6], v7 = src[7];
      uint4 o;
      o.x = pack8(v0, v1); o.y = pack8(v2, v3);
      o.z = pack8(v4, v5); o.w = pack8(v6, v7);
      xq[f] = o;  // fully coalesced: f is lane-consecutive
    }
  }
}

// async global->LDS, 16B per lane (wave-uniform base + lane*16)
__device__ __forceinline__ void load16(const uint8_t* g, uint8_t* l) {
  __builtin_amdgcn_global_load_lds(
      (const __attribute__((address_space(1))) uint32_t*)(uintptr_t)g,
      (__attribute__((address_space(3))) uint32_t*)(uintptr_t)l,
      16, 0, 0);
}

// ---------------- GEMM: C[m,n] = scale[n] * sum_k A[m,k]*B[n,k] ----------------
// A, B in fragment order (see header comment). mfma_scale 32x32x64 f8f6f4, FMT=4,
// scales pinned to 1.0 (e8m0 0x7F). fp32 accumulate exact for +-1 sums.
// 256 threads = 4 waves in 2x2; each wave does 64x64 via 2x2 of 32x32 tiles.
__global__ __launch_bounds__(256, 3) void gemm_bt_kernel(
    const uint8_t* __restrict__ A, const uint8_t* __restrict__ B,
    const float* __restrict__ scale, float* __restrict__ C,
    int M, int N, int K) {
  __shared__ __align__(16) uint8_t As[BM * 64];  // 4 groups x 128 frags x 16 B
  __shared__ __align__(16) uint8_t Bs[BN * 64];

  const int tid = threadIdx.x;
  const int lane = tid & 63;
  const int wave = tid >> 6;
  const int waveM = wave & 1;
  const int waveN = wave >> 1;
  const int kbT = K >> 7;  // K-tile iterations (64 B of K per iter)

  // XCD-aware bijective swizzle (nwg = gridDim.x*gridDim.y, divisible by 8)
  const int nwg = gridDim.x * gridDim.y;
  const int id = blockIdx.y * gridDim.x + blockIdx.x;
  const int swz = (id & 7) * (nwg >> 3) + (id >> 3);
  const int bx = swz % gridDim.x;
  const int by = swz / gridDim.x;

  // staging: wave w owns 32-row group w; 2 contiguous 1024-B loads per K-iter
  const uint8_t* aG = A + ((size_t)(by * 4 + wave) * kbT) * 2048 + lane * 16;
  const uint8_t* bG = B + ((size_t)(bx * 4 + wave) * kbT) * 2048 + lane * 16;
  uint8_t* aL = As + wave * 2048 + lane * 16;
  uint8_t* bL = Bs + wave * 2048 + lane * 16;

  // fragment reads: group (2*waveM+mi), p2 = s*64 + lane  ->  lane-linear
  const uint8_t* aF = As + waveM * 4096 + lane * 16;
  const uint8_t* bF = Bs + waveN * 4096 + lane * 16;

  f32x16 acc[2][2] = {};
  // persistent v8i32 operands; high 4 regs stay zero (fp4 uses low 4 only)
  i32x8 aop[2] = {}, bop[2] = {};

  for (int i = 0; i < kbT; ++i) {
    __syncthreads();  // previous iter's LDS reads done before overwrite
    const size_t o = (size_t)i * 2048;
    load16(aG + o, aL);
    load16(aG + o + 1024, aL + 1024);
    load16(bG + o, bL);
    load16(bG + o + 1024, bL + 1024);
    __syncthreads();  // staging complete (vmcnt drained before barrier)

#pragma unroll
    for (int s = 0; s < 2; ++s) {  // two K=64 MFMA steps per 64-B row tile
#pragma unroll
      for (int mi = 0; mi < 2; ++mi) {
        i32x4 t4 = *(const i32x4*)(aF + mi * 2048 + s * 1024);
        aop[mi].s0 = t4.x; aop[mi].s1 = t4.y; aop[mi].s2 = t4.z; aop[mi].s3 = t4.w;
      }
#pragma unroll
      for (int ni = 0; ni < 2; ++ni) {
        i32x4 t4 = *(const i32x4*)(bF + ni * 2048 + s * 1024);
        bop[ni].s0 = t4.x; bop[ni].s1 = t4.y; bop[ni].s2 = t4.z; bop[ni].s3 = t4.w;
      }
#pragma unroll
      for (int mi = 0; mi < 2; ++mi)
#pragma unroll
        for (int ni = 0; ni < 2; ++ni)
          acc[mi][ni] = __builtin_amdgcn_mfma_scale_f32_32x32x64_f8f6f4(
              aop[mi], bop[ni], acc[mi][ni],
              /*cbsz=fp4*/ 4, /*blgp=fp4*/ 4,
              /*opsel_a*/ 0, 0x7f7f7f7f, /*opsel_b*/ 0, 0x7f7f7f7f);
    }
  }

  // epilogue: 32x32 C/D layout col=lane&31, row=(reg&3)+8*(reg>>2)+4*(lane>>5)
  const int cCol = bx * BN + waveN * 64 + (lane & 31);
  const int cRowBase = by * BM + waveM * 64 + 4 * (lane >> 5);
  float sc[2];
#pragma unroll
  for (int ni = 0; ni < 2; ++ni) sc[ni] = scale[cCol + ni * 32];
#pragma unroll
  for (int mi = 0; mi < 2; ++mi)
#pragma unroll
    for (int ni = 0; ni < 2; ++ni)
#pragma unroll
      for (int r = 0; r < 16; ++r) {
        int row = cRowBase + mi * 32 + (r & 3) + 8 * (r >> 2);
        C[(size_t)row * N + cCol + ni * 32] = acc[mi][ni][r] * sc[ni];
      }
}

// ---------------- fallback (only if ws too small): exact, slow ----------------
__global__ void fallback_gemm(const float* __restrict__ X, const float* __restrict__ W,
                              float* __restrict__ C, int M, int N, int K) {
  __shared__ float xs[16][65];
  __shared__ float ws[16][65];
  __shared__ float wabs[256];
  __shared__ float scl[16];
  const int tx = threadIdx.x, ty = threadIdx.y;
  const int t = ty * 16 + tx;
  float acc = 0.f, wa = 0.f;
  for (int k0 = 0; k0 < K; k0 += 64) {
    __syncthreads();
#pragma unroll
    for (int j = 0; j < 4; ++j) {
      int e = t * 4 + j;
      int r = e >> 6, c = e & 63;
      float xv = X[(size_t)(blockIdx.y * 16 + r) * K + k0 + c];
      xs[r][c] = xv > 0.f ? 1.f : (xv < 0.f ? -1.f : 0.f);
      float wv = W[(size_t)(blockIdx.x * 16 + r) * K + k0 + c];
      ws[r][c] = wv > 0.f ? 1.f : (wv < 0.f ? -1.f : 0.f);
      wa += fabsf(wv);
    }
    __syncthreads();
#pragma unroll 8
    for (int k = 0; k < 64; ++k) acc += xs[ty][k] * ws[tx][k];
  }
  wabs[t] = wa;
  __syncthreads();
  for (int s2 = 8; s2 > 0; s2 >>= 1) {
    if (tx < s2) wabs[t] += wabs[t + s2];
    __syncthreads();
  }
  if (tx == 0) scl[ty] = wabs[t] / (float)K;
  __syncthreads();
  C[(size_t)(blockIdx.y * 16 + ty) * N + (blockIdx.x * 16 + tx)] = acc * scl[tx];
}

extern "C" void kernel_launch(void* const* d_in, const int* in_sizes, int n_in,
                              void* d_out, int out_size, void* d_ws, size_t ws_size,
                              hipStream_t stream) {
  const float* x = (const float*)d_in[0];
  const float* w = (const float*)d_in[1];
  float* out = (float*)d_out;

  const int K = 4096;
  const int N = in_sizes[1] / K;  // 4096
  const int M = in_sizes[0] / K;  // 8192

  size_t need = (size_t)M * (K / 2) + (size_t)N * (K / 2) + (size_t)N * sizeof(float);
  if (ws_size >= need) {
    uint8_t* Xq = (uint8_t*)d_ws;
    uint8_t* Wq = Xq + (size_t)M * (K / 2);
    float* scale = (float*)(Wq + (size_t)N * (K / 2));

    const int kbT = K >> 7;             // 32
    const int kbShift = __builtin_ctz(kbT);
    const int halfN = N / 2;            // weight blocks (2 rows each)
    const int xBlocks = (int)(((size_t)M * K / 32) / 1024);  // 1024 frags/block
    quant_fused_kernel<<<halfN + xBlocks, 256, 0, stream>>>(
        (const float4*)x, (uint4*)Xq, (const float4*)w, (uint4*)Wq,
        scale, halfN, K, kbShift);

    dim3 grid(N / BN, M / BM);
    gemm_bt_kernel<<<grid, 256, 0, stream>>>(Xq, Wq, scale, out, M, N, K);
  } else {
    dim3 grid(N / 16, M / 16);
    fallback_gemm<<<grid, dim3(16, 16), 0, stream>>>(x, w, out, M, N, K);
  }
}